// Round 1
// baseline (1326.831 us; speedup 1.0000x reference)
//
#include <hip/hip_runtime.h>
#include <stdint.h>

#define E_EDGES 800000
#define NN 50000
#define IN_CH 128
#define HID 64        // real hidden dims (32 complex)
#define OUT_CH 128
#define KTOT 192      // HID + IN_CH
#define BM 64

typedef __attribute__((ext_vector_type(8))) short short8;
typedef __attribute__((ext_vector_type(4))) float f32x4;

__device__ __forceinline__ uint32_t f2bf1(float f) {
    union { float f; uint32_t u; } v; v.f = f;
    return (v.u + 0x7FFFu + ((v.u >> 16) & 1u)) >> 16;  // RNE to bf16
}
__device__ __forceinline__ uint32_t pack2(float a, float b) {
    return f2bf1(a) | (f2bf1(b) << 16);
}

// ---- prep: repack weights to bf16, fuse biases ----
__global__ void prep_kernel(const float* __restrict__ W_in, const float* __restrict__ W_out,
                            const float* __restrict__ W_skip, const float* __restrict__ b_skip,
                            const float* __restrict__ bias,
                            unsigned short* __restrict__ Wb1,   // [64][128] bf16
                            unsigned short* __restrict__ Bt2,   // [128][192] bf16 (B^T: [n][k])
                            float* __restrict__ cb)             // [128]
{
    int t = blockIdx.x * blockDim.x + threadIdx.x;
    int stride = gridDim.x * blockDim.x;
    for (int i = t; i < HID * IN_CH; i += stride) Wb1[i] = (unsigned short)f2bf1(W_in[i]);
    for (int i = t; i < OUT_CH * KTOT; i += stride) {
        int n = i / KTOT, k = i % KTOT;
        float v = (k < HID) ? W_out[n * HID + k] : W_skip[n * IN_CH + (k - HID)];
        Bt2[i] = (unsigned short)f2bf1(v);
    }
    if (t < OUT_CH) cb[t] = b_skip[t] + bias[t];
}

// ---- k1: Z = attr @ W_in^T (bf16 MFMA), then complex scatter into h ----
__global__ __launch_bounds__(256)
void k1_kernel(const float* __restrict__ attr, const int* __restrict__ ei,
               const int* __restrict__ msk, const unsigned short* __restrict__ Wb1,
               float* __restrict__ h)
{
    __shared__ __align__(16) unsigned short sA[BM][136];   // attr tile bf16, pitch 136 (272B, 16B-mult)
    __shared__ __align__(16) unsigned short sW[HID][136];  // W_in bf16
    __shared__ float sZ[BM][68];                           // fp32 Z tile

    const int t  = threadIdx.x;
    const int e0 = blockIdx.x * BM;

    // stage W_in (8192 bf16 = 1024 x 16B)
    {
        const uint4* src = (const uint4*)Wb1;
        #pragma unroll
        for (int i = 0; i < 4; ++i) {
            int idx = t + i * 256;
            uint4 val = src[idx];
            *(uint4*)&sW[idx >> 4][(idx & 15) * 8] = val;
        }
    }
    // stage attr tile, fp32 -> bf16
    {
        int r = t >> 5, seg = t & 31;
        #pragma unroll
        for (int i = 0; i < 8; ++i) {
            int row = r + i * 8;
            float4 a = *(const float4*)&attr[(e0 + row) * IN_CH + seg * 4];
            uint2 pk; pk.x = pack2(a.x, a.y); pk.y = pack2(a.z, a.w);
            *(uint2*)&sA[row][seg * 4] = pk;
        }
    }
    __syncthreads();

    const int w = t >> 6, l = t & 63, lr = l & 15, quad = l >> 4;
    f32x4 acc[4] = {};
    #pragma unroll
    for (int kk = 0; kk < 4; ++kk) {
        short8 a = *(const short8*)&sA[w * 16 + lr][kk * 32 + quad * 8];
        #pragma unroll
        for (int nt = 0; nt < 4; ++nt) {
            short8 b = *(const short8*)&sW[nt * 16 + lr][kk * 32 + quad * 8];
            acc[nt] = __builtin_amdgcn_mfma_f32_16x16x32_bf16(a, b, acc[nt], 0, 0, 0);
        }
    }
    // C layout: col = lane&15, row = quad*4 + reg
    #pragma unroll
    for (int nt = 0; nt < 4; ++nt)
        #pragma unroll
        for (int r = 0; r < 4; ++r)
            sZ[w * 16 + quad * 4 + r][nt * 16 + lr] = acc[nt][r];
    __syncthreads();

    // scatter: 64 edges x 32 complex channels, 8 per thread
    #pragma unroll
    for (int i = 0; i < 8; ++i) {
        int idx = t + i * 256;
        int el = idx >> 5, c = idx & 31;
        int e = e0 + el;
        int u = ei[e], v = ei[E_EDGES + e];
        int mk = msk[e];
        float pr = mk ? 1.0f : 0.70710678f;
        float pi = mk ? 0.0f : 0.70710678f;
        float dinv = (u == v && mk) ? 0.0f : 0.70710678f;
        float zr = sZ[el][2 * c] * dinv;
        float zi = sZ[el][2 * c + 1] * dinv;
        // h[v] += conj(p) * z ; h[u] += (-p) * z
        atomicAdd(&h[v * HID + 2 * c],      pr * zr + pi * zi);
        atomicAdd(&h[v * HID + 2 * c + 1],  pr * zi - pi * zr);
        atomicAdd(&h[u * HID + 2 * c],     -(pr * zr - pi * zi));
        atomicAdd(&h[u * HID + 2 * c + 1], -(pr * zi + pi * zr));
    }
}

// ---- k2: gather h, build [y | attr] tile, MFMA with [W_out | W_skip]^T, + biases ----
__global__ __launch_bounds__(256)
void k2_kernel(const float* __restrict__ attr, const int* __restrict__ ei,
               const int* __restrict__ msk, const unsigned short* __restrict__ Bt2,
               const float* __restrict__ cb, const float* __restrict__ h,
               float* __restrict__ out)
{
    __shared__ __align__(16) unsigned short sA[BM][200];      // [64][192+8] (400B rows, 16B-mult)
    __shared__ __align__(16) unsigned short sB[OUT_CH][200];  // [128][192+8]

    const int t  = threadIdx.x;
    const int e0 = blockIdx.x * BM;

    // stage B^T (24576 bf16 = 3072 x 16B)
    #pragma unroll
    for (int i = 0; i < 12; ++i) {
        int idx = t + i * 256;
        int n = idx / 24, c = (idx % 24) * 8;
        uint4 val = *(const uint4*)&Bt2[n * KTOT + c];
        *(uint4*)&sB[n][c] = val;
    }
    // stage attr into k = 64..191
    {
        int r = t >> 5, seg = t & 31;
        #pragma unroll
        for (int i = 0; i < 8; ++i) {
            int row = r + i * 8;
            float4 a = *(const float4*)&attr[(e0 + row) * IN_CH + seg * 4];
            uint2 pk; pk.x = pack2(a.x, a.y); pk.y = pack2(a.z, a.w);
            *(uint2*)&sA[row][HID + seg * 4] = pk;
        }
    }
    // gather + relu + complex combine -> y into k = 0..63
    {
        int el = t >> 2, part = t & 3;
        int e = e0 + el;
        int u = ei[e], v = ei[E_EDGES + e];
        int mk = msk[e];
        float pr = mk ? 1.0f : 0.70710678f;
        float pi = mk ? 0.0f : 0.70710678f;
        float dinv = (u == v && mk) ? 0.0f : 0.70710678f;
        const float4* hv = (const float4*)&h[v * HID + part * 16];
        const float4* hu = (const float4*)&h[u * HID + part * 16];
        #pragma unroll
        for (int q = 0; q < 4; ++q) {
            float4 a4 = hv[q], b4 = hu[q];
            float ar0 = fmaxf(a4.x, 0.f), ai0 = fmaxf(a4.y, 0.f);
            float ar1 = fmaxf(a4.z, 0.f), ai1 = fmaxf(a4.w, 0.f);
            float br0 = fmaxf(b4.x, 0.f), bi0 = fmaxf(b4.y, 0.f);
            float br1 = fmaxf(b4.z, 0.f), bi1 = fmaxf(b4.w, 0.f);
            // y = dinv * ( p * relu(h[v]) - conj(p) * relu(h[u]) )
            float yr0 = dinv * ((pr * ar0 - pi * ai0) - (pr * br0 + pi * bi0));
            float yi0 = dinv * ((pr * ai0 + pi * ar0) - (pr * bi0 - pi * br0));
            float yr1 = dinv * ((pr * ar1 - pi * ai1) - (pr * br1 + pi * bi1));
            float yi1 = dinv * ((pr * ai1 + pi * ar1) - (pr * bi1 - pi * br1));
            uint2 pk; pk.x = pack2(yr0, yi0); pk.y = pack2(yr1, yi1);
            *(uint2*)&sA[el][part * 16 + q * 4] = pk;
        }
    }
    __syncthreads();

    const int w = t >> 6, l = t & 63, lr = l & 15, quad = l >> 4;
    f32x4 acc[8] = {};
    #pragma unroll
    for (int kk = 0; kk < 6; ++kk) {
        short8 a = *(const short8*)&sA[w * 16 + lr][kk * 32 + quad * 8];
        #pragma unroll
        for (int nt = 0; nt < 8; ++nt) {
            short8 b = *(const short8*)&sB[nt * 16 + lr][kk * 32 + quad * 8];
            acc[nt] = __builtin_amdgcn_mfma_f32_16x16x32_bf16(a, b, acc[nt], 0, 0, 0);
        }
    }
    #pragma unroll
    for (int nt = 0; nt < 8; ++nt) {
        int col = nt * 16 + lr;
        float cbv = cb[col];
        #pragma unroll
        for (int r = 0; r < 4; ++r) {
            int row = w * 16 + quad * 4 + r;
            out[(e0 + row) * OUT_CH + col] = acc[nt][r] + cbv;
        }
    }
}

extern "C" void kernel_launch(void* const* d_in, const int* in_sizes, int n_in,
                              void* d_out, int out_size, void* d_ws, size_t ws_size,
                              hipStream_t stream)
{
    const int*   ei    = (const int*)d_in[0];    // [2][E]
    const int*   msk   = (const int*)d_in[1];    // [E] bool as int
    const float* attr  = (const float*)d_in[2];  // [E][128]
    const float* W_in  = (const float*)d_in[3];  // [64][128]
    const float* W_out = (const float*)d_in[4];  // [128][64]
    const float* W_skp = (const float*)d_in[5];  // [128][128]
    const float* b_skp = (const float*)d_in[6];  // [128]
    const float* bias  = (const float*)d_in[7];  // [128]
    float* out = (float*)d_out;

    char* ws = (char*)d_ws;
    float*          h   = (float*)ws;                          // 12,800,000 B
    unsigned short* Wb1 = (unsigned short*)(ws + 12800000);    // 16,384 B
    unsigned short* Bt2 = (unsigned short*)(ws + 12816384);    // 49,152 B
    float*          cb  = (float*)(ws + 12865536);             // 512 B

    hipMemsetAsync(h, 0, (size_t)NN * HID * sizeof(float), stream);
    prep_kernel<<<64, 256, 0, stream>>>(W_in, W_out, W_skp, b_skp, bias, Wb1, Bt2, cb);
    k1_kernel<<<E_EDGES / BM, 256, 0, stream>>>(attr, ei, msk, Wb1, h);
    k2_kernel<<<E_EDGES / BM, 256, 0, stream>>>(attr, ei, msk, Bt2, cb, h, out);
}